// Round 7
// baseline (469.669 us; speedup 1.0000x reference)
//
#include <hip/hip_runtime.h>
#include <hip/hip_bf16.h>

#define D 128

typedef __attribute__((ext_vector_type(8))) short bf8;
typedef __attribute__((ext_vector_type(4))) float f4;

__device__ inline unsigned short f2bf(float f){
  unsigned u = __float_as_uint(f);
  unsigned r = (u + 0x7fff + ((u >> 16) & 1)) >> 16;  // RNE
  return (unsigned short)r;
}
__device__ inline float bflo(unsigned u){ return __uint_as_float(u << 16); }
__device__ inline float bfhi(unsigned u){ return __uint_as_float(u & 0xffff0000u); }

// ---------------- CSR build ----------------

__global__ __launch_bounds__(256) void k_count(const int* __restrict__ dst, int* __restrict__ counts, int E){
  int e = blockIdx.x * 256 + threadIdx.x;
  if (e < E) atomicAdd(&counts[dst[e]], 1);
}

__global__ __launch_bounds__(256) void k_blocksum(const int* __restrict__ counts, int* __restrict__ partial, int N){
  __shared__ int sm[256];
  int i = blockIdx.x * 256 + threadIdx.x;
  int v = (i < N) ? counts[i] : 0;
  sm[threadIdx.x] = v; __syncthreads();
  for (int off = 128; off; off >>= 1){
    if (threadIdx.x < off) sm[threadIdx.x] += sm[threadIdx.x + off];
    __syncthreads();
  }
  if (threadIdx.x == 0) partial[blockIdx.x] = sm[0];
}

// parallel scan of per-block partials (nb <= 256), one 256-thread block
__global__ __launch_bounds__(256) void k_scanpartial(const int* __restrict__ partial, int* __restrict__ poff, int nb,
                                                     int* __restrict__ row_start, int N){
  __shared__ int sm[256];
  int t = threadIdx.x;
  int v = (t < nb) ? partial[t] : 0;
  sm[t] = v; __syncthreads();
  for (int off = 1; off < 256; off <<= 1){
    int x = (t >= off) ? sm[t - off] : 0;
    __syncthreads();
    sm[t] += x;
    __syncthreads();
  }
  if (t < nb) poff[t] = sm[t] - v;          // exclusive
  if (t == 0) row_start[N] = sm[255];       // total E
}

__global__ __launch_bounds__(256) void k_blockscan(const int* __restrict__ counts, const int* __restrict__ poff,
                                                   int* __restrict__ row_start, int N){
  __shared__ int sm[256];
  int i = blockIdx.x * 256 + threadIdx.x;
  int v = (i < N) ? counts[i] : 0;
  sm[threadIdx.x] = v; __syncthreads();
  for (int off = 1; off < 256; off <<= 1){
    int t = (threadIdx.x >= off) ? sm[threadIdx.x - off] : 0;
    __syncthreads();
    sm[threadIdx.x] += t;
    __syncthreads();
  }
  if (i < N) row_start[i] = poff[blockIdx.x] + sm[threadIdx.x] - v;  // exclusive
}

// slot via atomicSub on counts (reversed order; sum is order-invariant). counts ends at 0.
__global__ __launch_bounds__(256) void k_fill(const int* __restrict__ src, const int* __restrict__ dst,
                                              const int* __restrict__ row_start, int* __restrict__ counts,
                                              int* __restrict__ srcs, int E){
  int e = blockIdx.x * 256 + threadIdx.x;
  if (e < E){
    int d = dst[e];
    int v = atomicSub(&counts[d], 1);
    srcs[row_start[d] + v - 1] = src[e];
  }
}

// ---------------- casts / packing ----------------

__global__ __launch_bounds__(256) void k_cast(const float* __restrict__ in, unsigned short* __restrict__ outb, int n8){
  int i = blockIdx.x * 256 + threadIdx.x;
  if (i >= n8) return;
  const float4* p = (const float4*)(in + (size_t)i * 8);
  float4 a = p[0], b = p[1];
  union { unsigned short s[8]; uint4 u; } o;
  o.s[0]=f2bf(a.x); o.s[1]=f2bf(a.y); o.s[2]=f2bf(a.z); o.s[3]=f2bf(a.w);
  o.s[4]=f2bf(b.x); o.s[5]=f2bf(b.y); o.s[6]=f2bf(b.z); o.s[7]=f2bf(b.w);
  *(uint4*)(outb + (size_t)i * 8) = o.u;
}

// WT[m][n][k] = Wm[k][n], m 0..3 -> W1 layer m, m 4..7 -> W2 layer m-4
__global__ __launch_bounds__(256) void k_packWT(const float* __restrict__ W1, const float* __restrict__ W2,
                                                unsigned short* __restrict__ WT){
  int idx = blockIdx.x * 256 + threadIdx.x;     // 8*128*128 = 131072
  int m = idx >> 14;
  int r = idx & 16383;
  int n = r >> 7, k = r & 127;
  const float* W = (m < 4) ? (W1 + (size_t)m * D * D) : (W2 + (size_t)(m - 4) * D * D);
  WT[idx] = f2bf(W[(size_t)k * D + n]);
}

// ---------------- Fused GIN layer: out = act2(relu((h+aggN(h))@W1+b1)@W2 + b2) ----------------
// Barrier-free: wave w owns rows w*16..w*16+15 of the 64-row block tile for
// gather, both GEMMs, and the z1 handoff (all via its own Al rows). W is read
// directly from global (32KB, L1/L2-hot, identical across waves). LDS = Al only
// (17.4KB) -> 8 blocks/CU, 32 waves/CU; gather latency overlaps MFMA across waves.

template<int LAST>
__global__ __launch_bounds__(256) void k_layer(const unsigned short* __restrict__ h,
                                               const int* __restrict__ row_start,
                                               const int* __restrict__ srcs,
                                               const unsigned short* __restrict__ WT1,
                                               const float* __restrict__ b1,
                                               const unsigned short* __restrict__ WT2,
                                               const float* __restrict__ b2,
                                               unsigned short* __restrict__ out, int M){
  __shared__ unsigned short Al[64 * 136];    // 17.4 KB, padded stride 272 B
  int tid = threadIdx.x;
  int row0 = blockIdx.x * 64;
  int w = tid >> 6, lane = tid & 63;
  int g = lane >> 4, sl = lane & 15;
  const uint4* h4 = (const uint4*)h;        // one row = 16 uint4

  // ---- gather: z-row(node) = h[node] + sum h[srcs], wave-private Al rows ----
  for (int i = 0; i < 16; ++i){
    int node = row0 + w * 16 + i;
    float a0=0,a1=0,a2=0,a3=0,a4=0,a5=0,a6=0,a7=0;
    if (node < M){
      if (g == 0){   // self term folded into group 0
        uint4 v = h4[(size_t)node * 16 + sl];
        a0 += bflo(v.x); a1 += bfhi(v.x); a2 += bflo(v.y); a3 += bfhi(v.y);
        a4 += bflo(v.z); a5 += bfhi(v.z); a6 += bflo(v.w); a7 += bfhi(v.w);
      }
      int beg = row_start[node], end = row_start[node + 1];
      int e = beg + g;
      for (; e + 4 < end; e += 8){
        int s0 = srcs[e], s1 = srcs[e + 4];
        uint4 v0 = h4[(size_t)s0 * 16 + sl];
        uint4 v1 = h4[(size_t)s1 * 16 + sl];
        a0 += bflo(v0.x) + bflo(v1.x); a1 += bfhi(v0.x) + bfhi(v1.x);
        a2 += bflo(v0.y) + bflo(v1.y); a3 += bfhi(v0.y) + bfhi(v1.y);
        a4 += bflo(v0.z) + bflo(v1.z); a5 += bfhi(v0.z) + bfhi(v1.z);
        a6 += bflo(v0.w) + bflo(v1.w); a7 += bfhi(v0.w) + bfhi(v1.w);
      }
      if (e < end){
        uint4 v = h4[(size_t)srcs[e] * 16 + sl];
        a0 += bflo(v.x); a1 += bfhi(v.x); a2 += bflo(v.y); a3 += bfhi(v.y);
        a4 += bflo(v.z); a5 += bfhi(v.z); a6 += bflo(v.w); a7 += bfhi(v.w);
      }
    }
    // combine 4 row-groups (butterfly: all lanes end with totals)
    a0 += __shfl_xor(a0, 16); a1 += __shfl_xor(a1, 16);
    a2 += __shfl_xor(a2, 16); a3 += __shfl_xor(a3, 16);
    a4 += __shfl_xor(a4, 16); a5 += __shfl_xor(a5, 16);
    a6 += __shfl_xor(a6, 16); a7 += __shfl_xor(a7, 16);
    a0 += __shfl_xor(a0, 32); a1 += __shfl_xor(a1, 32);
    a2 += __shfl_xor(a2, 32); a3 += __shfl_xor(a3, 32);
    a4 += __shfl_xor(a4, 32); a5 += __shfl_xor(a5, 32);
    a6 += __shfl_xor(a6, 32); a7 += __shfl_xor(a7, 32);
    if (g == 0){
      uint4 o;
      o.x = ((unsigned)f2bf(a1) << 16) | (unsigned)f2bf(a0);
      o.y = ((unsigned)f2bf(a3) << 16) | (unsigned)f2bf(a2);
      o.z = ((unsigned)f2bf(a5) << 16) | (unsigned)f2bf(a4);
      o.w = ((unsigned)f2bf(a7) << 16) | (unsigned)f2bf(a6);
      *(uint4*)&Al[(w * 16 + i) * 136 + sl * 8] = o;
    }
  }
  // no __syncthreads: Al rows are wave-private throughout

  int lr = lane & 15, lk = (lane >> 4) * 8;
  f4 acc[8];
  bf8 af[4];

  // ---- GEMM1: z @ W1 (B-frags straight from global WT1) ----
  #pragma unroll
  for (int i = 0; i < 8; ++i) acc[i] = (f4)(0.f);
  #pragma unroll
  for (int ks = 0; ks < 4; ++ks) af[ks] = *(const bf8*)&Al[(w * 16 + lr) * 136 + ks * 32 + lk];
  #pragma unroll
  for (int nt = 0; nt < 8; ++nt)
    #pragma unroll
    for (int ks = 0; ks < 4; ++ks){
      bf8 b = *(const bf8*)&WT1[(size_t)(nt * 16 + lr) * D + ks * 32 + lk];
      acc[nt] = __builtin_amdgcn_mfma_f32_16x16x32_bf16(af[ks], b, acc[nt], 0, 0, 0);
    }
  // z1 = relu(acc + b1) -> own Al rows
  {
    int rbase = w * 16 + (lane >> 4) * 4;
    #pragma unroll
    for (int nt = 0; nt < 8; ++nt){
      int col = nt * 16 + lr;
      float bb = b1[col];
      #pragma unroll
      for (int j = 0; j < 4; ++j)
        Al[(rbase + j) * 136 + col] = f2bf(fmaxf(acc[nt][j] + bb, 0.f));
    }
  }
  // ---- GEMM2: z1 @ W2 ----
  #pragma unroll
  for (int i = 0; i < 8; ++i) acc[i] = (f4)(0.f);
  #pragma unroll
  for (int ks = 0; ks < 4; ++ks) af[ks] = *(const bf8*)&Al[(w * 16 + lr) * 136 + ks * 32 + lk];
  #pragma unroll
  for (int nt = 0; nt < 8; ++nt)
    #pragma unroll
    for (int ks = 0; ks < 4; ++ks){
      bf8 b = *(const bf8*)&WT2[(size_t)(nt * 16 + lr) * D + ks * 32 + lk];
      acc[nt] = __builtin_amdgcn_mfma_f32_16x16x32_bf16(af[ks], b, acc[nt], 0, 0, 0);
    }
  // epilogue
  {
    int rbase = row0 + w * 16 + (lane >> 4) * 4;
    #pragma unroll
    for (int nt = 0; nt < 8; ++nt){
      int col = nt * 16 + lr;
      float bb = b2[col];
      #pragma unroll
      for (int j = 0; j < 4; ++j){
        int row = rbase + j;
        if (row < M){
          float v = acc[nt][j] + bb;
          if (!LAST) v = fmaxf(v, 0.f);
          out[(size_t)row * D + col] = f2bf(v);
        }
      }
    }
  }
}

// ---------------- Global add pool (batch sorted), h is bf16 ----------------

__global__ __launch_bounds__(256) void k_pool(const unsigned short* __restrict__ hb, const int* __restrict__ batch,
                                              float* __restrict__ hG, int N){
  int g = blockIdx.x * 256 + threadIdx.x;
  int chunk = g >> 5;        // 16-node run
  int dg = g & 31;           // 4-dim group
  int n0 = chunk * 16;
  if (n0 >= N) return;
  int n1 = n0 + 16; if (n1 > N) n1 = N;
  float ax = 0.f, ay = 0.f, az = 0.f, aw = 0.f;
  int cur = batch[n0];
  for (int n = n0; n < n1; ++n){
    int b = batch[n];
    uint2 v = *(const uint2*)&hb[(size_t)n * D + dg * 4];
    if (b != cur){
      float* p = &hG[(size_t)cur * D + dg * 4];
      atomicAdd(p + 0, ax); atomicAdd(p + 1, ay); atomicAdd(p + 2, az); atomicAdd(p + 3, aw);
      ax = ay = az = aw = 0.f; cur = b;
    }
    ax += bflo(v.x); ay += bfhi(v.x); az += bflo(v.y); aw += bfhi(v.y);
  }
  float* p = &hG[(size_t)cur * D + dg * 4];
  atomicAdd(p + 0, ax); atomicAdd(p + 1, ay); atomicAdd(p + 2, az); atomicAdd(p + 3, aw);
}

// ---------------- Head ----------------

__global__ __launch_bounds__(64) void k_head(const float* __restrict__ hG, const float* __restrict__ lw,
                                             const float* __restrict__ lb, float* __restrict__ out){
  int gph = blockIdx.x;
  int lane = threadIdx.x;
  float logit = -INFINITY;
  if (lane < 10){
    float s = lb[lane];
    const float* hg = &hG[(size_t)gph * D];
    #pragma unroll 8
    for (int k = 0; k < D; ++k) s += hg[k] * lw[k * 10 + lane];
    logit = s;
  }
  float m = logit;
  for (int off = 32; off; off >>= 1) m = fmaxf(m, __shfl_down(m, off));
  m = __shfl(m, 0);
  float e = (lane < 10) ? expf(logit - m) : 0.f;
  float ssum = e;
  for (int off = 32; off; off >>= 1) ssum += __shfl_down(ssum, off);
  ssum = __shfl(ssum, 0);
  if (lane < 10) out[(size_t)gph * 10 + lane] = logit - m - logf(ssum);
}

// ---------------- launch ----------------

extern "C" void kernel_launch(void* const* d_in, const int* in_sizes, int n_in,
                              void* d_out, int out_size, void* d_ws, size_t ws_size,
                              hipStream_t stream){
  const float* x  = (const float*)d_in[0];
  const int*   ei = (const int*)d_in[1];
  const int*   batch = (const int*)d_in[2];
  const float* W1 = (const float*)d_in[3];
  const float* b1 = (const float*)d_in[4];
  const float* W2 = (const float*)d_in[5];
  const float* b2 = (const float*)d_in[6];
  const float* lw = (const float*)d_in[7];
  const float* lb = (const float*)d_in[8];
  float* out = (float*)d_out;

  int N = in_sizes[0] / D;       // 50000
  int E = in_sizes[1] / 2;       // 600000
  int G = out_size / (D + 10);   // 500
  const int* src = ei;
  const int* dst = ei + E;

  char* w = (char*)d_ws;
  size_t off = 0;
  auto alloc = [&](size_t bytes) -> char* {
    char* p = w + off;
    off = (off + bytes + 255) & ~(size_t)255;
    return p;
  };
  unsigned short* h_bf  = (unsigned short*)alloc((size_t)N * D * 2);
  unsigned short* h2_bf = (unsigned short*)alloc((size_t)N * D * 2);
  unsigned short* WT    = (unsigned short*)alloc((size_t)8 * D * D * 2);
  int nb = (N + 255) / 256;
  int* row_start = (int*)alloc((size_t)(N + 1) * 4);
  int* counts    = (int*)alloc((size_t)N * 4);
  int* partial   = (int*)alloc((size_t)nb * 4);
  int* poff      = (int*)alloc((size_t)nb * 4);
  int* srcs      = (int*)alloc((size_t)E * 4);

  hipMemsetAsync(counts, 0, (size_t)N * 4, stream);
  hipMemsetAsync(d_out,  0, (size_t)out_size * 4, stream);

  int n8 = N * D / 8;
  k_cast<<<(n8 + 255) / 256, 256, 0, stream>>>(x, h_bf, n8);
  k_packWT<<<512, 256, 0, stream>>>(W1, W2, WT);

  int ge = (E + 255) / 256;
  k_count<<<ge, 256, 0, stream>>>(dst, counts, E);
  k_blocksum<<<nb, 256, 0, stream>>>(counts, partial, N);
  k_scanpartial<<<1, 256, 0, stream>>>(partial, poff, nb, row_start, N);
  k_blockscan<<<nb, 256, 0, stream>>>(counts, poff, row_start, N);
  k_fill<<<ge, 256, 0, stream>>>(src, dst, row_start, counts, srcs, E);

  int gm = (N + 63) / 64;
  unsigned short* hin  = h_bf;
  unsigned short* hout = h2_bf;
  for (int i = 0; i < 4; ++i){
    if (i < 3)
      k_layer<0><<<gm, 256, 0, stream>>>(hin, row_start, srcs,
                                         WT + (size_t)i * D * D, b1 + (size_t)i * D,
                                         WT + (size_t)(4 + i) * D * D, b2 + (size_t)i * D, hout, N);
    else
      k_layer<1><<<gm, 256, 0, stream>>>(hin, row_start, srcs,
                                         WT + (size_t)i * D * D, b1 + (size_t)i * D,
                                         WT + (size_t)(4 + i) * D * D, b2 + (size_t)i * D, hout, N);
    unsigned short* t = hin; hin = hout; hout = t;
  }

  int gp = (((N + 15) / 16) * 32 + 255) / 256;
  k_pool<<<gp, 256, 0, stream>>>(hin, batch, out, N);
  k_head<<<G, 64, 0, stream>>>(out, lw, lb, out + (size_t)G * D);
}

// Round 8
// 443.239 us; speedup vs baseline: 1.0596x; 1.0596x over previous
//
#include <hip/hip_runtime.h>
#include <hip/hip_bf16.h>

#define D 128

typedef __attribute__((ext_vector_type(8))) short bf8;
typedef __attribute__((ext_vector_type(4))) float f4;

__device__ inline unsigned short f2bf(float f){
  unsigned u = __float_as_uint(f);
  unsigned r = (u + 0x7fff + ((u >> 16) & 1)) >> 16;  // RNE
  return (unsigned short)r;
}
__device__ inline float bflo(unsigned u){ return __uint_as_float(u << 16); }
__device__ inline float bfhi(unsigned u){ return __uint_as_float(u & 0xffff0000u); }

// ---------------- CSR build ----------------

__global__ __launch_bounds__(256) void k_count(const int* __restrict__ dst, int* __restrict__ counts, int E){
  int e = blockIdx.x * 256 + threadIdx.x;
  if (e < E) atomicAdd(&counts[dst[e]], 1);
}

__global__ __launch_bounds__(256) void k_blocksum(const int* __restrict__ counts, int* __restrict__ partial, int N){
  __shared__ int sm[256];
  int i = blockIdx.x * 256 + threadIdx.x;
  int v = (i < N) ? counts[i] : 0;
  sm[threadIdx.x] = v; __syncthreads();
  for (int off = 128; off; off >>= 1){
    if (threadIdx.x < off) sm[threadIdx.x] += sm[threadIdx.x + off];
    __syncthreads();
  }
  if (threadIdx.x == 0) partial[blockIdx.x] = sm[0];
}

// parallel scan of per-block partials (nb <= 256), one 256-thread block
__global__ __launch_bounds__(256) void k_scanpartial(const int* __restrict__ partial, int* __restrict__ poff, int nb,
                                                     int* __restrict__ row_start, int N){
  __shared__ int sm[256];
  int t = threadIdx.x;
  int v = (t < nb) ? partial[t] : 0;
  sm[t] = v; __syncthreads();
  for (int off = 1; off < 256; off <<= 1){
    int x = (t >= off) ? sm[t - off] : 0;
    __syncthreads();
    sm[t] += x;
    __syncthreads();
  }
  if (t < nb) poff[t] = sm[t] - v;          // exclusive
  if (t == 0) row_start[N] = sm[255];       // total E
}

__global__ __launch_bounds__(256) void k_blockscan(const int* __restrict__ counts, const int* __restrict__ poff,
                                                   int* __restrict__ row_start, int N){
  __shared__ int sm[256];
  int i = blockIdx.x * 256 + threadIdx.x;
  int v = (i < N) ? counts[i] : 0;
  sm[threadIdx.x] = v; __syncthreads();
  for (int off = 1; off < 256; off <<= 1){
    int t = (threadIdx.x >= off) ? sm[threadIdx.x - off] : 0;
    __syncthreads();
    sm[threadIdx.x] += t;
    __syncthreads();
  }
  if (i < N) row_start[i] = poff[blockIdx.x] + sm[threadIdx.x] - v;  // exclusive
}

// slot via atomicSub on counts (reversed order; sum is order-invariant). counts ends at 0.
__global__ __launch_bounds__(256) void k_fill(const int* __restrict__ src, const int* __restrict__ dst,
                                              const int* __restrict__ row_start, int* __restrict__ counts,
                                              int* __restrict__ srcs, int E){
  int e = blockIdx.x * 256 + threadIdx.x;
  if (e < E){
    int d = dst[e];
    int v = atomicSub(&counts[d], 1);
    srcs[row_start[d] + v - 1] = src[e];
  }
}

// ---------------- casts / packing ----------------

__global__ __launch_bounds__(256) void k_cast(const float* __restrict__ in, unsigned short* __restrict__ outb, int n8){
  int i = blockIdx.x * 256 + threadIdx.x;
  if (i >= n8) return;
  const float4* p = (const float4*)(in + (size_t)i * 8);
  float4 a = p[0], b = p[1];
  union { unsigned short s[8]; uint4 u; } o;
  o.s[0]=f2bf(a.x); o.s[1]=f2bf(a.y); o.s[2]=f2bf(a.z); o.s[3]=f2bf(a.w);
  o.s[4]=f2bf(b.x); o.s[5]=f2bf(b.y); o.s[6]=f2bf(b.z); o.s[7]=f2bf(b.w);
  *(uint4*)(outb + (size_t)i * 8) = o.u;
}

// WT[m][n][k] = Wm[k][n], m 0..3 -> W1 layer m, m 4..7 -> W2 layer m-4
__global__ __launch_bounds__(256) void k_packWT(const float* __restrict__ W1, const float* __restrict__ W2,
                                                unsigned short* __restrict__ WT){
  int idx = blockIdx.x * 256 + threadIdx.x;     // 8*128*128 = 131072
  int m = idx >> 14;
  int r = idx & 16383;
  int n = r >> 7, k = r & 127;
  const float* W = (m < 4) ? (W1 + (size_t)m * D * D) : (W2 + (size_t)(m - 4) * D * D);
  WT[idx] = f2bf(W[(size_t)k * D + n]);
}

// ---------------- Aggregation (bf16): z[n] = h[n] + sum h[src] ----------------
// One wave per node (high occupancy for the latency-bound gather).
// 4 row-groups x 16 lanes; one load instruction covers 4 edges' rows.

__global__ __launch_bounds__(256) void k_agg(const unsigned short* __restrict__ hb, const int* __restrict__ row_start,
                                             const int* __restrict__ srcs, unsigned short* __restrict__ zb, int N){
  int wid  = (blockIdx.x * 256 + threadIdx.x) >> 6;
  int lane = threadIdx.x & 63;
  if (wid >= N) return;
  int g  = lane >> 4;        // row-group 0..3
  int sl = lane & 15;        // 16B slice within row
  const uint4* h4 = (const uint4*)hb;   // one row = 16 uint4

  float a0=0,a1=0,a2=0,a3=0,a4=0,a5=0,a6=0,a7=0;
  if (g == 0){               // fold self row into group 0
    uint4 v = h4[(size_t)wid * 16 + sl];
    a0 += bflo(v.x); a1 += bfhi(v.x); a2 += bflo(v.y); a3 += bfhi(v.y);
    a4 += bflo(v.z); a5 += bfhi(v.z); a6 += bflo(v.w); a7 += bfhi(v.w);
  }
  int beg = row_start[wid], end = row_start[wid + 1];
  int e = beg + g;
  for (; e + 4 < end; e += 8){
    int s0 = srcs[e], s1 = srcs[e + 4];
    uint4 v0 = h4[(size_t)s0 * 16 + sl];
    uint4 v1 = h4[(size_t)s1 * 16 + sl];
    a0 += bflo(v0.x) + bflo(v1.x); a1 += bfhi(v0.x) + bfhi(v1.x);
    a2 += bflo(v0.y) + bflo(v1.y); a3 += bfhi(v0.y) + bfhi(v1.y);
    a4 += bflo(v0.z) + bflo(v1.z); a5 += bfhi(v0.z) + bfhi(v1.z);
    a6 += bflo(v0.w) + bflo(v1.w); a7 += bfhi(v0.w) + bfhi(v1.w);
  }
  if (e < end){
    uint4 v = h4[(size_t)srcs[e] * 16 + sl];
    a0 += bflo(v.x); a1 += bfhi(v.x); a2 += bflo(v.y); a3 += bfhi(v.y);
    a4 += bflo(v.z); a5 += bfhi(v.z); a6 += bflo(v.w); a7 += bfhi(v.w);
  }
  // combine the 4 row-groups (lanes l, l^16, l^32, l^48)
  a0 += __shfl_xor(a0, 16); a1 += __shfl_xor(a1, 16);
  a2 += __shfl_xor(a2, 16); a3 += __shfl_xor(a3, 16);
  a4 += __shfl_xor(a4, 16); a5 += __shfl_xor(a5, 16);
  a6 += __shfl_xor(a6, 16); a7 += __shfl_xor(a7, 16);
  a0 += __shfl_xor(a0, 32); a1 += __shfl_xor(a1, 32);
  a2 += __shfl_xor(a2, 32); a3 += __shfl_xor(a3, 32);
  a4 += __shfl_xor(a4, 32); a5 += __shfl_xor(a5, 32);
  a6 += __shfl_xor(a6, 32); a7 += __shfl_xor(a7, 32);
  if (g == 0){
    uint4 o;
    o.x = ((unsigned)f2bf(a1) << 16) | (unsigned)f2bf(a0);
    o.y = ((unsigned)f2bf(a3) << 16) | (unsigned)f2bf(a2);
    o.z = ((unsigned)f2bf(a5) << 16) | (unsigned)f2bf(a4);
    o.w = ((unsigned)f2bf(a7) << 16) | (unsigned)f2bf(a6);
    ((uint4*)zb)[(size_t)wid * 16 + sl] = o;
  }
}

// ---------------- MLP: out = act2(relu(A@W1+b1)@W2 + b2) ----------------
// Barrier-free: wave w stages ONLY its own 16 rows into its own Al segment and
// reads only those (incl. the z1 handoff). W1/W2 B-fragments are read directly
// from global (32KB each, L1/L2-hot). LDS = 17.4KB, VGPR ~64.

template<int LAST>
__global__ __launch_bounds__(256) void k_mlp(const unsigned short* __restrict__ A,
                                             const unsigned short* __restrict__ WT1,
                                             const float* __restrict__ b1,
                                             const unsigned short* __restrict__ WT2,
                                             const float* __restrict__ b2,
                                             unsigned short* __restrict__ out, int M){
  __shared__ unsigned short Al[64 * 136];    // padded stride 272 B
  int tid = threadIdx.x;
  int row0 = blockIdx.x * 64;
  int w = tid >> 6, lane = tid & 63;

  // wave-private stage: 4 lanes per row, 64B per lane
  {
    int r = w * 16 + (lane >> 2);
    int c = (lane & 3) * 32;             // 32 bf16 = 64B
    int row = row0 + r;
    uint4 v0 = make_uint4(0,0,0,0), v1 = v0, v2 = v0, v3 = v0;
    if (row < M){
      const uint4* p = (const uint4*)&A[(size_t)row * D + c];
      v0 = p[0]; v1 = p[1]; v2 = p[2]; v3 = p[3];
    }
    uint4* q = (uint4*)&Al[r * 136 + c];
    q[0] = v0; q[1] = v1; q[2] = v2; q[3] = v3;
  }
  // no __syncthreads: Al rows are wave-private throughout

  int lr = lane & 15, lk = (lane >> 4) * 8;
  f4 acc[8];
  bf8 af[4];

  // ---- GEMM1: z @ W1 (B-frags from global) ----
  #pragma unroll
  for (int i = 0; i < 8; ++i) acc[i] = (f4)(0.f);
  #pragma unroll
  for (int ks = 0; ks < 4; ++ks) af[ks] = *(const bf8*)&Al[(w * 16 + lr) * 136 + ks * 32 + lk];
  #pragma unroll
  for (int nt = 0; nt < 8; ++nt)
    #pragma unroll
    for (int ks = 0; ks < 4; ++ks){
      bf8 b = *(const bf8*)&WT1[(size_t)(nt * 16 + lr) * D + ks * 32 + lk];
      acc[nt] = __builtin_amdgcn_mfma_f32_16x16x32_bf16(af[ks], b, acc[nt], 0, 0, 0);
    }
  // z1 = relu(acc + b1) -> own Al rows
  {
    int rbase = w * 16 + (lane >> 4) * 4;
    #pragma unroll
    for (int nt = 0; nt < 8; ++nt){
      int col = nt * 16 + lr;
      float bb = b1[col];
      #pragma unroll
      for (int j = 0; j < 4; ++j)
        Al[(rbase + j) * 136 + col] = f2bf(fmaxf(acc[nt][j] + bb, 0.f));
    }
  }
  // ---- GEMM2: z1 @ W2 ----
  #pragma unroll
  for (int i = 0; i < 8; ++i) acc[i] = (f4)(0.f);
  #pragma unroll
  for (int ks = 0; ks < 4; ++ks) af[ks] = *(const bf8*)&Al[(w * 16 + lr) * 136 + ks * 32 + lk];
  #pragma unroll
  for (int nt = 0; nt < 8; ++nt)
    #pragma unroll
    for (int ks = 0; ks < 4; ++ks){
      bf8 b = *(const bf8*)&WT2[(size_t)(nt * 16 + lr) * D + ks * 32 + lk];
      acc[nt] = __builtin_amdgcn_mfma_f32_16x16x32_bf16(af[ks], b, acc[nt], 0, 0, 0);
    }
  // epilogue
  {
    int rbase = row0 + w * 16 + (lane >> 4) * 4;
    #pragma unroll
    for (int nt = 0; nt < 8; ++nt){
      int col = nt * 16 + lr;
      float bb = b2[col];
      #pragma unroll
      for (int j = 0; j < 4; ++j){
        int row = rbase + j;
        if (row < M){
          float v = acc[nt][j] + bb;
          if (!LAST) v = fmaxf(v, 0.f);
          out[(size_t)row * D + col] = f2bf(v);
        }
      }
    }
  }
}

// ---------------- Global add pool (batch sorted), h is bf16 ----------------

__global__ __launch_bounds__(256) void k_pool(const unsigned short* __restrict__ hb, const int* __restrict__ batch,
                                              float* __restrict__ hG, int N){
  int g = blockIdx.x * 256 + threadIdx.x;
  int chunk = g >> 5;        // 16-node run
  int dg = g & 31;           // 4-dim group
  int n0 = chunk * 16;
  if (n0 >= N) return;
  int n1 = n0 + 16; if (n1 > N) n1 = N;
  float ax = 0.f, ay = 0.f, az = 0.f, aw = 0.f;
  int cur = batch[n0];
  for (int n = n0; n < n1; ++n){
    int b = batch[n];
    uint2 v = *(const uint2*)&hb[(size_t)n * D + dg * 4];
    if (b != cur){
      float* p = &hG[(size_t)cur * D + dg * 4];
      atomicAdd(p + 0, ax); atomicAdd(p + 1, ay); atomicAdd(p + 2, az); atomicAdd(p + 3, aw);
      ax = ay = az = aw = 0.f; cur = b;
    }
    ax += bflo(v.x); ay += bfhi(v.x); az += bflo(v.y); aw += bfhi(v.y);
  }
  float* p = &hG[(size_t)cur * D + dg * 4];
  atomicAdd(p + 0, ax); atomicAdd(p + 1, ay); atomicAdd(p + 2, az); atomicAdd(p + 3, aw);
}

// ---------------- Head ----------------

__global__ __launch_bounds__(64) void k_head(const float* __restrict__ hG, const float* __restrict__ lw,
                                             const float* __restrict__ lb, float* __restrict__ out){
  int gph = blockIdx.x;
  int lane = threadIdx.x;
  float logit = -INFINITY;
  if (lane < 10){
    float s = lb[lane];
    const float* hg = &hG[(size_t)gph * D];
    #pragma unroll 8
    for (int k = 0; k < D; ++k) s += hg[k] * lw[k * 10 + lane];
    logit = s;
  }
  float m = logit;
  for (int off = 32; off; off >>= 1) m = fmaxf(m, __shfl_down(m, off));
  m = __shfl(m, 0);
  float e = (lane < 10) ? expf(logit - m) : 0.f;
  float ssum = e;
  for (int off = 32; off; off >>= 1) ssum += __shfl_down(ssum, off);
  ssum = __shfl(ssum, 0);
  if (lane < 10) out[(size_t)gph * 10 + lane] = logit - m - logf(ssum);
}

// ---------------- launch ----------------

extern "C" void kernel_launch(void* const* d_in, const int* in_sizes, int n_in,
                              void* d_out, int out_size, void* d_ws, size_t ws_size,
                              hipStream_t stream){
  const float* x  = (const float*)d_in[0];
  const int*   ei = (const int*)d_in[1];
  const int*   batch = (const int*)d_in[2];
  const float* W1 = (const float*)d_in[3];
  const float* b1 = (const float*)d_in[4];
  const float* W2 = (const float*)d_in[5];
  const float* b2 = (const float*)d_in[6];
  const float* lw = (const float*)d_in[7];
  const float* lb = (const float*)d_in[8];
  float* out = (float*)d_out;

  int N = in_sizes[0] / D;       // 50000
  int E = in_sizes[1] / 2;       // 600000
  int G = out_size / (D + 10);   // 500
  const int* src = ei;
  const int* dst = ei + E;

  char* w = (char*)d_ws;
  size_t off = 0;
  auto alloc = [&](size_t bytes) -> char* {
    char* p = w + off;
    off = (off + bytes + 255) & ~(size_t)255;
    return p;
  };
  unsigned short* h_bf  = (unsigned short*)alloc((size_t)N * D * 2);
  unsigned short* h2_bf = (unsigned short*)alloc((size_t)N * D * 2);
  unsigned short* z_bf  = (unsigned short*)alloc((size_t)N * D * 2);
  unsigned short* WT    = (unsigned short*)alloc((size_t)8 * D * D * 2);
  int nb = (N + 255) / 256;
  int* row_start = (int*)alloc((size_t)(N + 1) * 4);
  int* counts    = (int*)alloc((size_t)N * 4);
  int* partial   = (int*)alloc((size_t)nb * 4);
  int* poff      = (int*)alloc((size_t)nb * 4);
  int* srcs      = (int*)alloc((size_t)E * 4);

  hipMemsetAsync(counts, 0, (size_t)N * 4, stream);
  hipMemsetAsync(d_out,  0, (size_t)out_size * 4, stream);

  int n8 = N * D / 8;
  k_cast<<<(n8 + 255) / 256, 256, 0, stream>>>(x, h_bf, n8);
  k_packWT<<<512, 256, 0, stream>>>(W1, W2, WT);

  int ge = (E + 255) / 256;
  k_count<<<ge, 256, 0, stream>>>(dst, counts, E);
  k_blocksum<<<nb, 256, 0, stream>>>(counts, partial, N);
  k_scanpartial<<<1, 256, 0, stream>>>(partial, poff, nb, row_start, N);
  k_blockscan<<<nb, 256, 0, stream>>>(counts, poff, row_start, N);
  k_fill<<<ge, 256, 0, stream>>>(src, dst, row_start, counts, srcs, E);

  int gagg = (N + 3) / 4;
  int gm = (N + 63) / 64;
  unsigned short* hin  = h_bf;
  unsigned short* hout = h2_bf;
  for (int i = 0; i < 4; ++i){
    k_agg<<<gagg, 256, 0, stream>>>(hin, row_start, srcs, z_bf, N);
    if (i < 3)
      k_mlp<0><<<gm, 256, 0, stream>>>(z_bf, WT + (size_t)i * D * D, b1 + (size_t)i * D,
                                       WT + (size_t)(4 + i) * D * D, b2 + (size_t)i * D, hout, N);
    else
      k_mlp<1><<<gm, 256, 0, stream>>>(z_bf, WT + (size_t)i * D * D, b1 + (size_t)i * D,
                                       WT + (size_t)(4 + i) * D * D, b2 + (size_t)i * D, hout, N);
    unsigned short* t = hin; hin = hout; hout = t;
  }

  int gp = (((N + 15) / 16) * 32 + 255) / 256;
  k_pool<<<gp, 256, 0, stream>>>(hin, batch, out, N);
  k_head<<<G, 64, 0, stream>>>(out, lw, lb, out + (size_t)G * D);
}

// Round 10
// 376.414 us; speedup vs baseline: 1.2477x; 1.1775x over previous
//
#include <hip/hip_runtime.h>
#include <hip/hip_bf16.h>

#define D 128

typedef __attribute__((ext_vector_type(8))) short bf8;
typedef __attribute__((ext_vector_type(4))) float f4;

__device__ inline unsigned short f2bf(float f){
  unsigned u = __float_as_uint(f);
  unsigned r = (u + 0x7fff + ((u >> 16) & 1)) >> 16;  // RNE
  return (unsigned short)r;
}
__device__ inline float bflo(unsigned u){ return __uint_as_float(u << 16); }
__device__ inline float bfhi(unsigned u){ return __uint_as_float(u & 0xffff0000u); }

// ---------------- CSR build ----------------

__global__ __launch_bounds__(256) void k_count(const int* __restrict__ dst, int* __restrict__ counts, int E){
  int e = blockIdx.x * 256 + threadIdx.x;
  if (e < E) atomicAdd(&counts[dst[e]], 1);
}

__global__ __launch_bounds__(256) void k_blocksum(const int* __restrict__ counts, int* __restrict__ partial, int N){
  __shared__ int sm[256];
  int i = blockIdx.x * 256 + threadIdx.x;
  int v = (i < N) ? counts[i] : 0;
  sm[threadIdx.x] = v; __syncthreads();
  for (int off = 128; off; off >>= 1){
    if (threadIdx.x < off) sm[threadIdx.x] += sm[threadIdx.x + off];
    __syncthreads();
  }
  if (threadIdx.x == 0) partial[blockIdx.x] = sm[0];
}

// parallel scan of per-block partials (nb <= 256), one 256-thread block
__global__ __launch_bounds__(256) void k_scanpartial(const int* __restrict__ partial, int* __restrict__ poff, int nb,
                                                     int* __restrict__ row_start, int N){
  __shared__ int sm[256];
  int t = threadIdx.x;
  int v = (t < nb) ? partial[t] : 0;
  sm[t] = v; __syncthreads();
  for (int off = 1; off < 256; off <<= 1){
    int x = (t >= off) ? sm[t - off] : 0;
    __syncthreads();
    sm[t] += x;
    __syncthreads();
  }
  if (t < nb) poff[t] = sm[t] - v;          // exclusive
  if (t == 0) row_start[N] = sm[255];       // total E
}

__global__ __launch_bounds__(256) void k_blockscan(const int* __restrict__ counts, const int* __restrict__ poff,
                                                   int* __restrict__ row_start, int N){
  __shared__ int sm[256];
  int i = blockIdx.x * 256 + threadIdx.x;
  int v = (i < N) ? counts[i] : 0;
  sm[threadIdx.x] = v; __syncthreads();
  for (int off = 1; off < 256; off <<= 1){
    int t = (threadIdx.x >= off) ? sm[threadIdx.x - off] : 0;
    __syncthreads();
    sm[threadIdx.x] += t;
    __syncthreads();
  }
  if (i < N) row_start[i] = poff[blockIdx.x] + sm[threadIdx.x] - v;  // exclusive
}

// slot via atomicSub on counts (reversed order; sum is order-invariant). counts ends at 0.
__global__ __launch_bounds__(256) void k_fill(const int* __restrict__ src, const int* __restrict__ dst,
                                              const int* __restrict__ row_start, int* __restrict__ counts,
                                              int* __restrict__ srcs, int E){
  int e = blockIdx.x * 256 + threadIdx.x;
  if (e < E){
    int d = dst[e];
    int v = atomicSub(&counts[d], 1);
    srcs[row_start[d] + v - 1] = src[e];
  }
}

// ---------------- casts / packing ----------------

__global__ __launch_bounds__(256) void k_cast(const float* __restrict__ in, unsigned short* __restrict__ outb, int n8){
  int i = blockIdx.x * 256 + threadIdx.x;
  if (i >= n8) return;
  const float4* p = (const float4*)(in + (size_t)i * 8);
  float4 a = p[0], b = p[1];
  union { unsigned short s[8]; uint4 u; } o;
  o.s[0]=f2bf(a.x); o.s[1]=f2bf(a.y); o.s[2]=f2bf(a.z); o.s[3]=f2bf(a.w);
  o.s[4]=f2bf(b.x); o.s[5]=f2bf(b.y); o.s[6]=f2bf(b.z); o.s[7]=f2bf(b.w);
  *(uint4*)(outb + (size_t)i * 8) = o.u;
}

// WT[m][n][k] = Wm[k][n], m 0..3 -> W1 layer m, m 4..7 -> W2 layer m-4
__global__ __launch_bounds__(256) void k_packWT(const float* __restrict__ W1, const float* __restrict__ W2,
                                                unsigned short* __restrict__ WT){
  int idx = blockIdx.x * 256 + threadIdx.x;     // 8*128*128 = 131072
  int m = idx >> 14;
  int r = idx & 16383;
  int n = r >> 7, k = r & 127;
  const float* W = (m < 4) ? (W1 + (size_t)m * D * D) : (W2 + (size_t)(m - 4) * D * D);
  WT[idx] = f2bf(W[(size_t)k * D + n]);
}

// ---------------- Aggregation (bf16): z[n] = h[n] + sum h[src] ----------------
// One wave per node. Lane-parallel index prefetch (64 indices/one coalesced load,
// shfl broadcast). Inner loop is WAVE-UNIFORM (base+8<=cnt) so every __shfl
// executes with all 64 lanes active; tail runs once with predicated adds.

__global__ __launch_bounds__(256) void k_agg(const unsigned short* __restrict__ hb, const int* __restrict__ row_start,
                                             const int* __restrict__ srcs, unsigned short* __restrict__ zb, int N){
  int wid  = (blockIdx.x * 256 + threadIdx.x) >> 6;
  int lane = threadIdx.x & 63;
  if (wid >= N) return;
  int g  = lane >> 4;        // row-group 0..3
  int sl = lane & 15;        // 16B slice within row
  const uint4* h4 = (const uint4*)hb;   // one row = 16 uint4

  float a0=0,a1=0,a2=0,a3=0,a4=0,a5=0,a6=0,a7=0;
  if (g == 0){               // fold self row into group 0
    uint4 v = h4[(size_t)wid * 16 + sl];
    a0 += bflo(v.x); a1 += bfhi(v.x); a2 += bflo(v.y); a3 += bfhi(v.y);
    a4 += bflo(v.z); a5 += bfhi(v.z); a6 += bflo(v.w); a7 += bfhi(v.w);
  }
  int beg = row_start[wid], end = row_start[wid + 1];
  int deg = end - beg;
  for (int chunk = 0; chunk < deg; chunk += 64){
    int rem = deg - chunk;
    int cnt = rem < 64 ? rem : 64;                                    // uniform
    int myidx = (chunk + lane < deg) ? srcs[beg + chunk + lane] : 0;  // one coalesced load
    int base = 0;
    // uniform trip count: j0=base+g<=base+3<cnt, j1=base+g+4<=base+7<cnt — all lanes active
    for (; base + 8 <= cnt; base += 8){
      int s0 = __shfl(myidx, base + g);
      int s1 = __shfl(myidx, base + g + 4);
      uint4 v0 = h4[(size_t)s0 * 16 + sl];
      uint4 v1 = h4[(size_t)s1 * 16 + sl];
      a0 += bflo(v0.x) + bflo(v1.x); a1 += bfhi(v0.x) + bfhi(v1.x);
      a2 += bflo(v0.y) + bflo(v1.y); a3 += bfhi(v0.y) + bfhi(v1.y);
      a4 += bflo(v0.z) + bflo(v1.z); a5 += bfhi(v0.z) + bfhi(v1.z);
      a6 += bflo(v0.w) + bflo(v1.w); a7 += bfhi(v0.w) + bfhi(v1.w);
    }
    if (base < cnt){           // uniform entry; shfls run full-exec, adds predicated
      int j0 = base + g, j1 = base + g + 4;
      int s0 = __shfl(myidx, j0 < cnt ? j0 : 0);
      int s1 = __shfl(myidx, j1 < cnt ? j1 : 0);
      if (j0 < cnt){
        uint4 v = h4[(size_t)s0 * 16 + sl];
        a0 += bflo(v.x); a1 += bfhi(v.x); a2 += bflo(v.y); a3 += bfhi(v.y);
        a4 += bflo(v.z); a5 += bfhi(v.z); a6 += bflo(v.w); a7 += bfhi(v.w);
      }
      if (j1 < cnt){
        uint4 v = h4[(size_t)s1 * 16 + sl];
        a0 += bflo(v.x); a1 += bfhi(v.x); a2 += bflo(v.y); a3 += bfhi(v.y);
        a4 += bflo(v.z); a5 += bfhi(v.z); a6 += bflo(v.w); a7 += bfhi(v.w);
      }
    }
  }
  // combine the 4 row-groups (lanes l, l^16, l^32, l^48)
  a0 += __shfl_xor(a0, 16); a1 += __shfl_xor(a1, 16);
  a2 += __shfl_xor(a2, 16); a3 += __shfl_xor(a3, 16);
  a4 += __shfl_xor(a4, 16); a5 += __shfl_xor(a5, 16);
  a6 += __shfl_xor(a6, 16); a7 += __shfl_xor(a7, 16);
  a0 += __shfl_xor(a0, 32); a1 += __shfl_xor(a1, 32);
  a2 += __shfl_xor(a2, 32); a3 += __shfl_xor(a3, 32);
  a4 += __shfl_xor(a4, 32); a5 += __shfl_xor(a5, 32);
  a6 += __shfl_xor(a6, 32); a7 += __shfl_xor(a7, 32);
  if (g == 0){
    uint4 o;
    o.x = ((unsigned)f2bf(a1) << 16) | (unsigned)f2bf(a0);
    o.y = ((unsigned)f2bf(a3) << 16) | (unsigned)f2bf(a2);
    o.z = ((unsigned)f2bf(a5) << 16) | (unsigned)f2bf(a4);
    o.w = ((unsigned)f2bf(a7) << 16) | (unsigned)f2bf(a6);
    ((uint4*)zb)[(size_t)wid * 16 + sl] = o;
  }
}

// ---------------- Fused MLP (R6-proven): out = act2(relu(A@W1+b1)@W2 + b2) ----------------
// W staged in LDS (ds_read for MFMA B-frags), A-tile staged, z1 handoff in Al
// (wave-private rows). 3 barriers, 52KB LDS -> 3 blocks/CU.

template<int LAST>
__global__ __launch_bounds__(256) void k_mlp(const unsigned short* __restrict__ A,
                                             const unsigned short* __restrict__ WT1,
                                             const float* __restrict__ b1,
                                             const unsigned short* __restrict__ WT2,
                                             const float* __restrict__ b2,
                                             unsigned short* __restrict__ out, int M){
  __shared__ unsigned short Wl[128 * 136];   // 34.8 KB, padded stride 272 B
  __shared__ unsigned short Al[64 * 136];    // 17.4 KB
  int tid = threadIdx.x;
  int row0 = blockIdx.x * 64;
  int w = tid >> 6, lane = tid & 63;
  int lr = lane & 15, lk = (lane >> 4) * 8;
  int rr = tid >> 4, cc = (tid & 15) * 8;

  // stage W1 + A tile
  #pragma unroll
  for (int it = 0; it < 8; ++it){
    int r = it * 16 + rr;
    *(uint4*)&Wl[r * 136 + cc] = *(const uint4*)&WT1[(size_t)r * D + cc];
  }
  #pragma unroll
  for (int it = 0; it < 4; ++it){
    int r = it * 16 + rr;
    int row = row0 + r;
    uint4 v = make_uint4(0, 0, 0, 0);
    if (row < M) v = *(const uint4*)&A[(size_t)row * D + cc];
    *(uint4*)&Al[r * 136 + cc] = v;
  }
  __syncthreads();

  f4 acc[8];
  bf8 af[4];
  // ---- GEMM1 ----
  #pragma unroll
  for (int i = 0; i < 8; ++i) acc[i] = (f4)(0.f);
  #pragma unroll
  for (int ks = 0; ks < 4; ++ks) af[ks] = *(const bf8*)&Al[(w * 16 + lr) * 136 + ks * 32 + lk];
  #pragma unroll
  for (int nt = 0; nt < 8; ++nt)
    #pragma unroll
    for (int ks = 0; ks < 4; ++ks){
      bf8 b = *(const bf8*)&Wl[(nt * 16 + lr) * 136 + ks * 32 + lk];
      acc[nt] = __builtin_amdgcn_mfma_f32_16x16x32_bf16(af[ks], b, acc[nt], 0, 0, 0);
    }
  // z1 = relu(acc + b1) -> own Al rows
  {
    int rbase = w * 16 + (lane >> 4) * 4;
    #pragma unroll
    for (int nt = 0; nt < 8; ++nt){
      int col = nt * 16 + lr;
      float bb = b1[col];
      #pragma unroll
      for (int j = 0; j < 4; ++j)
        Al[(rbase + j) * 136 + col] = f2bf(fmaxf(acc[nt][j] + bb, 0.f));
    }
  }
  __syncthreads();   // everyone done reading Wl(W1)
  // stage W2
  #pragma unroll
  for (int it = 0; it < 8; ++it){
    int r = it * 16 + rr;
    *(uint4*)&Wl[r * 136 + cc] = *(const uint4*)&WT2[(size_t)r * D + cc];
  }
  __syncthreads();
  // ---- GEMM2 ----
  #pragma unroll
  for (int i = 0; i < 8; ++i) acc[i] = (f4)(0.f);
  #pragma unroll
  for (int ks = 0; ks < 4; ++ks) af[ks] = *(const bf8*)&Al[(w * 16 + lr) * 136 + ks * 32 + lk];
  #pragma unroll
  for (int nt = 0; nt < 8; ++nt)
    #pragma unroll
    for (int ks = 0; ks < 4; ++ks){
      bf8 b = *(const bf8*)&Wl[(nt * 16 + lr) * 136 + ks * 32 + lk];
      acc[nt] = __builtin_amdgcn_mfma_f32_16x16x32_bf16(af[ks], b, acc[nt], 0, 0, 0);
    }
  // epilogue
  {
    int rbase = row0 + w * 16 + (lane >> 4) * 4;
    #pragma unroll
    for (int nt = 0; nt < 8; ++nt){
      int col = nt * 16 + lr;
      float bb = b2[col];
      #pragma unroll
      for (int j = 0; j < 4; ++j){
        int row = rbase + j;
        if (row < M){
          float v = acc[nt][j] + bb;
          if (!LAST) v = fmaxf(v, 0.f);
          out[(size_t)row * D + col] = f2bf(v);
        }
      }
    }
  }
}

// ---------------- Global add pool (batch sorted), h is bf16 ----------------

__global__ __launch_bounds__(256) void k_pool(const unsigned short* __restrict__ hb, const int* __restrict__ batch,
                                              float* __restrict__ hG, int N){
  int g = blockIdx.x * 256 + threadIdx.x;
  int chunk = g >> 5;        // 16-node run
  int dg = g & 31;           // 4-dim group
  int n0 = chunk * 16;
  if (n0 >= N) return;
  int n1 = n0 + 16; if (n1 > N) n1 = N;
  float ax = 0.f, ay = 0.f, az = 0.f, aw = 0.f;
  int cur = batch[n0];
  for (int n = n0; n < n1; ++n){
    int b = batch[n];
    uint2 v = *(const uint2*)&hb[(size_t)n * D + dg * 4];
    if (b != cur){
      float* p = &hG[(size_t)cur * D + dg * 4];
      atomicAdd(p + 0, ax); atomicAdd(p + 1, ay); atomicAdd(p + 2, az); atomicAdd(p + 3, aw);
      ax = ay = az = aw = 0.f; cur = b;
    }
    ax += bflo(v.x); ay += bfhi(v.x); az += bflo(v.y); aw += bfhi(v.y);
  }
  float* p = &hG[(size_t)cur * D + dg * 4];
  atomicAdd(p + 0, ax); atomicAdd(p + 1, ay); atomicAdd(p + 2, az); atomicAdd(p + 3, aw);
}

// ---------------- Head ----------------

__global__ __launch_bounds__(64) void k_head(const float* __restrict__ hG, const float* __restrict__ lw,
                                             const float* __restrict__ lb, float* __restrict__ out){
  int gph = blockIdx.x;
  int lane = threadIdx.x;
  float logit = -INFINITY;
  if (lane < 10){
    float s = lb[lane];
    const float* hg = &hG[(size_t)gph * D];
    #pragma unroll 8
    for (int k = 0; k < D; ++k) s += hg[k] * lw[k * 10 + lane];
    logit = s;
  }
  float m = logit;
  for (int off = 32; off; off >>= 1) m = fmaxf(m, __shfl_down(m, off));
  m = __shfl(m, 0);
  float e = (lane < 10) ? expf(logit - m) : 0.f;
  float ssum = e;
  for (int off = 32; off; off >>= 1) ssum += __shfl_down(ssum, off);
  ssum = __shfl(ssum, 0);
  if (lane < 10) out[(size_t)gph * 10 + lane] = logit - m - logf(ssum);
}

// ---------------- launch ----------------

extern "C" void kernel_launch(void* const* d_in, const int* in_sizes, int n_in,
                              void* d_out, int out_size, void* d_ws, size_t ws_size,
                              hipStream_t stream){
  const float* x  = (const float*)d_in[0];
  const int*   ei = (const int*)d_in[1];
  const int*   batch = (const int*)d_in[2];
  const float* W1 = (const float*)d_in[3];
  const float* b1 = (const float*)d_in[4];
  const float* W2 = (const float*)d_in[5];
  const float* b2 = (const float*)d_in[6];
  const float* lw = (const float*)d_in[7];
  const float* lb = (const float*)d_in[8];
  float* out = (float*)d_out;

  int N = in_sizes[0] / D;       // 50000
  int E = in_sizes[1] / 2;       // 600000
  int G = out_size / (D + 10);   // 500
  const int* src = ei;
  const int* dst = ei + E;

  char* w = (char*)d_ws;
  size_t off = 0;
  auto alloc = [&](size_t bytes) -> char* {
    char* p = w + off;
    off = (off + bytes + 255) & ~(size_t)255;
    return p;
  };
  unsigned short* h_bf  = (unsigned short*)alloc((size_t)N * D * 2);
  unsigned short* z_bf  = (unsigned short*)alloc((size_t)N * D * 2);
  unsigned short* WT    = (unsigned short*)alloc((size_t)8 * D * D * 2);
  int nb = (N + 255) / 256;
  int* row_start = (int*)alloc((size_t)(N + 1) * 4);
  int* counts    = (int*)alloc((size_t)N * 4);
  int* partial   = (int*)alloc((size_t)nb * 4);
  int* poff      = (int*)alloc((size_t)nb * 4);
  int* srcs      = (int*)alloc((size_t)E * 4);

  hipMemsetAsync(counts, 0, (size_t)N * 4, stream);
  hipMemsetAsync(d_out,  0, (size_t)out_size * 4, stream);

  int n8 = N * D / 8;
  k_cast<<<(n8 + 255) / 256, 256, 0, stream>>>(x, h_bf, n8);
  k_packWT<<<512, 256, 0, stream>>>(W1, W2, WT);

  int ge = (E + 255) / 256;
  k_count<<<ge, 256, 0, stream>>>(dst, counts, E);
  k_blocksum<<<nb, 256, 0, stream>>>(counts, partial, N);
  k_scanpartial<<<1, 256, 0, stream>>>(partial, poff, nb, row_start, N);
  k_blockscan<<<nb, 256, 0, stream>>>(counts, poff, row_start, N);
  k_fill<<<ge, 256, 0, stream>>>(src, dst, row_start, counts, srcs, E);

  int gagg = (N + 3) / 4;
  int gm = (N + 63) / 64;
  for (int i = 0; i < 4; ++i){
    k_agg<<<gagg, 256, 0, stream>>>(h_bf, row_start, srcs, z_bf, N);
    if (i < 3)
      k_mlp<0><<<gm, 256, 0, stream>>>(z_bf, WT + (size_t)i * D * D, b1 + (size_t)i * D,
                                       WT + (size_t)(4 + i) * D * D, b2 + (size_t)i * D, h_bf, N);
    else
      k_mlp<1><<<gm, 256, 0, stream>>>(z_bf, WT + (size_t)i * D * D, b1 + (size_t)i * D,
                                       WT + (size_t)(4 + i) * D * D, b2 + (size_t)i * D, h_bf, N);
  }

  int gp = (((N + 15) / 16) * 32 + 255) / 256;
  k_pool<<<gp, 256, 0, stream>>>(h_bf, batch, out, N);
  k_head<<<G, 64, 0, stream>>>(out, lw, lb, out + (size_t)G * D);
}

// Round 11
// 369.463 us; speedup vs baseline: 1.2712x; 1.0188x over previous
//
#include <hip/hip_runtime.h>
#include <hip/hip_bf16.h>

#define D 128

typedef __attribute__((ext_vector_type(8))) short bf8;
typedef __attribute__((ext_vector_type(4))) float f4;

__device__ inline unsigned short f2bf(float f){
  unsigned u = __float_as_uint(f);
  unsigned r = (u + 0x7fff + ((u >> 16) & 1)) >> 16;  // RNE
  return (unsigned short)r;
}
__device__ inline float bflo(unsigned u){ return __uint_as_float(u << 16); }
__device__ inline float bfhi(unsigned u){ return __uint_as_float(u & 0xffff0000u); }

// ---------------- CSR build ----------------

__global__ __launch_bounds__(256) void k_count(const int* __restrict__ dst, int* __restrict__ counts, int E){
  int e = blockIdx.x * 256 + threadIdx.x;
  if (e < E) atomicAdd(&counts[dst[e]], 1);
}

__global__ __launch_bounds__(256) void k_blocksum(const int* __restrict__ counts, int* __restrict__ partial, int N){
  __shared__ int sm[256];
  int i = blockIdx.x * 256 + threadIdx.x;
  int v = (i < N) ? counts[i] : 0;
  sm[threadIdx.x] = v; __syncthreads();
  for (int off = 128; off; off >>= 1){
    if (threadIdx.x < off) sm[threadIdx.x] += sm[threadIdx.x + off];
    __syncthreads();
  }
  if (threadIdx.x == 0) partial[blockIdx.x] = sm[0];
}

// parallel scan of per-block partials (nb <= 256), one 256-thread block
__global__ __launch_bounds__(256) void k_scanpartial(const int* __restrict__ partial, int* __restrict__ poff, int nb,
                                                     int* __restrict__ row_start, int N){
  __shared__ int sm[256];
  int t = threadIdx.x;
  int v = (t < nb) ? partial[t] : 0;
  sm[t] = v; __syncthreads();
  for (int off = 1; off < 256; off <<= 1){
    int x = (t >= off) ? sm[t - off] : 0;
    __syncthreads();
    sm[t] += x;
    __syncthreads();
  }
  if (t < nb) poff[t] = sm[t] - v;          // exclusive
  if (t == 0) row_start[N] = sm[255];       // total E
}

__global__ __launch_bounds__(256) void k_blockscan(const int* __restrict__ counts, const int* __restrict__ poff,
                                                   int* __restrict__ row_start, int N){
  __shared__ int sm[256];
  int i = blockIdx.x * 256 + threadIdx.x;
  int v = (i < N) ? counts[i] : 0;
  sm[threadIdx.x] = v; __syncthreads();
  for (int off = 1; off < 256; off <<= 1){
    int t = (threadIdx.x >= off) ? sm[threadIdx.x - off] : 0;
    __syncthreads();
    sm[threadIdx.x] += t;
    __syncthreads();
  }
  if (i < N) row_start[i] = poff[blockIdx.x] + sm[threadIdx.x] - v;  // exclusive
}

// slot via atomicSub on counts (reversed order; sum is order-invariant). counts ends at 0.
__global__ __launch_bounds__(256) void k_fill(const int* __restrict__ src, const int* __restrict__ dst,
                                              const int* __restrict__ row_start, int* __restrict__ counts,
                                              int* __restrict__ srcs, int E){
  int e = blockIdx.x * 256 + threadIdx.x;
  if (e < E){
    int d = dst[e];
    int v = atomicSub(&counts[d], 1);
    srcs[row_start[d] + v - 1] = src[e];
  }
}

// ---------------- casts / packing ----------------

__global__ __launch_bounds__(256) void k_cast(const float* __restrict__ in, unsigned short* __restrict__ outb, int n8){
  int i = blockIdx.x * 256 + threadIdx.x;
  if (i >= n8) return;
  const float4* p = (const float4*)(in + (size_t)i * 8);
  float4 a = p[0], b = p[1];
  union { unsigned short s[8]; uint4 u; } o;
  o.s[0]=f2bf(a.x); o.s[1]=f2bf(a.y); o.s[2]=f2bf(a.z); o.s[3]=f2bf(a.w);
  o.s[4]=f2bf(b.x); o.s[5]=f2bf(b.y); o.s[6]=f2bf(b.z); o.s[7]=f2bf(b.w);
  *(uint4*)(outb + (size_t)i * 8) = o.u;
}

// WT[m][n][k] = Wm[k][n], m 0..3 -> W1 layer m, m 4..7 -> W2 layer m-4
__global__ __launch_bounds__(256) void k_packWT(const float* __restrict__ W1, const float* __restrict__ W2,
                                                unsigned short* __restrict__ WT){
  int idx = blockIdx.x * 256 + threadIdx.x;     // 8*128*128 = 131072
  int m = idx >> 14;
  int r = idx & 16383;
  int n = r >> 7, k = r & 127;
  const float* W = (m < 4) ? (W1 + (size_t)m * D * D) : (W2 + (size_t)(m - 4) * D * D);
  WT[idx] = f2bf(W[(size_t)k * D + n]);
}

// ---------------- Aggregation (bf16): z[n] = h[n] + sum h[src] ----------------
// 4 nodes per wave, one per 16-lane group. Each group gathers its node's full
// 256B rows (16B/lane); srcs index is a group-uniform load (merged request).
// No cross-lane combines. Latency chain amortized over 4 nodes; 4 groups x
// unroll-4 row loads in flight per wave. Waves: 12500 (vs 50000).

__global__ __launch_bounds__(256) void k_agg(const unsigned short* __restrict__ hb, const int* __restrict__ row_start,
                                             const int* __restrict__ srcs, unsigned short* __restrict__ zb, int N){
  int wave = (blockIdx.x * 256 + threadIdx.x) >> 6;
  int lane = threadIdx.x & 63;
  int g = lane >> 4, sl = lane & 15;
  int node = wave * 4 + g;
  if (node >= N) return;
  const uint4* h4 = (const uint4*)hb;   // one row = 16 uint4

  uint4 v = h4[(size_t)node * 16 + sl];   // self
  float a0 = bflo(v.x), a1 = bfhi(v.x), a2 = bflo(v.y), a3 = bfhi(v.y);
  float a4 = bflo(v.z), a5 = bfhi(v.z), a6 = bflo(v.w), a7 = bfhi(v.w);

  int beg = row_start[node], end = row_start[node + 1];
  int e = beg;
  for (; e + 4 <= end; e += 4){
    int s0 = srcs[e], s1 = srcs[e + 1], s2 = srcs[e + 2], s3 = srcs[e + 3];
    uint4 v0 = h4[(size_t)s0 * 16 + sl];
    uint4 v1 = h4[(size_t)s1 * 16 + sl];
    uint4 v2 = h4[(size_t)s2 * 16 + sl];
    uint4 v3 = h4[(size_t)s3 * 16 + sl];
    a0 += bflo(v0.x) + bflo(v1.x) + bflo(v2.x) + bflo(v3.x);
    a1 += bfhi(v0.x) + bfhi(v1.x) + bfhi(v2.x) + bfhi(v3.x);
    a2 += bflo(v0.y) + bflo(v1.y) + bflo(v2.y) + bflo(v3.y);
    a3 += bfhi(v0.y) + bfhi(v1.y) + bfhi(v2.y) + bfhi(v3.y);
    a4 += bflo(v0.z) + bflo(v1.z) + bflo(v2.z) + bflo(v3.z);
    a5 += bfhi(v0.z) + bfhi(v1.z) + bfhi(v2.z) + bfhi(v3.z);
    a6 += bflo(v0.w) + bflo(v1.w) + bflo(v2.w) + bflo(v3.w);
    a7 += bfhi(v0.w) + bfhi(v1.w) + bfhi(v2.w) + bfhi(v3.w);
  }
  for (; e < end; ++e){
    uint4 vv = h4[(size_t)srcs[e] * 16 + sl];
    a0 += bflo(vv.x); a1 += bfhi(vv.x); a2 += bflo(vv.y); a3 += bfhi(vv.y);
    a4 += bflo(vv.z); a5 += bfhi(vv.z); a6 += bflo(vv.w); a7 += bfhi(vv.w);
  }
  uint4 o;
  o.x = ((unsigned)f2bf(a1) << 16) | (unsigned)f2bf(a0);
  o.y = ((unsigned)f2bf(a3) << 16) | (unsigned)f2bf(a2);
  o.z = ((unsigned)f2bf(a5) << 16) | (unsigned)f2bf(a4);
  o.w = ((unsigned)f2bf(a7) << 16) | (unsigned)f2bf(a6);
  ((uint4*)zb)[(size_t)node * 16 + sl] = o;
}

// ---------------- Fused MLP (R6-proven): out = act2(relu(A@W1+b1)@W2 + b2) ----------------
// W staged in LDS (ds_read for MFMA B-frags), A-tile staged, z1 handoff in Al
// (wave-private rows). 3 barriers, 52KB LDS -> 3 blocks/CU.

template<int LAST>
__global__ __launch_bounds__(256) void k_mlp(const unsigned short* __restrict__ A,
                                             const unsigned short* __restrict__ WT1,
                                             const float* __restrict__ b1,
                                             const unsigned short* __restrict__ WT2,
                                             const float* __restrict__ b2,
                                             unsigned short* __restrict__ out, int M){
  __shared__ unsigned short Wl[128 * 136];   // 34.8 KB, padded stride 272 B
  __shared__ unsigned short Al[64 * 136];    // 17.4 KB
  int tid = threadIdx.x;
  int row0 = blockIdx.x * 64;
  int w = tid >> 6, lane = tid & 63;
  int lr = lane & 15, lk = (lane >> 4) * 8;
  int rr = tid >> 4, cc = (tid & 15) * 8;

  // stage W1 + A tile
  #pragma unroll
  for (int it = 0; it < 8; ++it){
    int r = it * 16 + rr;
    *(uint4*)&Wl[r * 136 + cc] = *(const uint4*)&WT1[(size_t)r * D + cc];
  }
  #pragma unroll
  for (int it = 0; it < 4; ++it){
    int r = it * 16 + rr;
    int row = row0 + r;
    uint4 v = make_uint4(0, 0, 0, 0);
    if (row < M) v = *(const uint4*)&A[(size_t)row * D + cc];
    *(uint4*)&Al[r * 136 + cc] = v;
  }
  __syncthreads();

  f4 acc[8];
  bf8 af[4];
  // ---- GEMM1 ----
  #pragma unroll
  for (int i = 0; i < 8; ++i) acc[i] = (f4)(0.f);
  #pragma unroll
  for (int ks = 0; ks < 4; ++ks) af[ks] = *(const bf8*)&Al[(w * 16 + lr) * 136 + ks * 32 + lk];
  #pragma unroll
  for (int nt = 0; nt < 8; ++nt)
    #pragma unroll
    for (int ks = 0; ks < 4; ++ks){
      bf8 b = *(const bf8*)&Wl[(nt * 16 + lr) * 136 + ks * 32 + lk];
      acc[nt] = __builtin_amdgcn_mfma_f32_16x16x32_bf16(af[ks], b, acc[nt], 0, 0, 0);
    }
  // z1 = relu(acc + b1) -> own Al rows
  {
    int rbase = w * 16 + (lane >> 4) * 4;
    #pragma unroll
    for (int nt = 0; nt < 8; ++nt){
      int col = nt * 16 + lr;
      float bb = b1[col];
      #pragma unroll
      for (int j = 0; j < 4; ++j)
        Al[(rbase + j) * 136 + col] = f2bf(fmaxf(acc[nt][j] + bb, 0.f));
    }
  }
  __syncthreads();   // everyone done reading Wl(W1)
  // stage W2
  #pragma unroll
  for (int it = 0; it < 8; ++it){
    int r = it * 16 + rr;
    *(uint4*)&Wl[r * 136 + cc] = *(const uint4*)&WT2[(size_t)r * D + cc];
  }
  __syncthreads();
  // ---- GEMM2 ----
  #pragma unroll
  for (int i = 0; i < 8; ++i) acc[i] = (f4)(0.f);
  #pragma unroll
  for (int ks = 0; ks < 4; ++ks) af[ks] = *(const bf8*)&Al[(w * 16 + lr) * 136 + ks * 32 + lk];
  #pragma unroll
  for (int nt = 0; nt < 8; ++nt)
    #pragma unroll
    for (int ks = 0; ks < 4; ++ks){
      bf8 b = *(const bf8*)&Wl[(nt * 16 + lr) * 136 + ks * 32 + lk];
      acc[nt] = __builtin_amdgcn_mfma_f32_16x16x32_bf16(af[ks], b, acc[nt], 0, 0, 0);
    }
  // epilogue
  {
    int rbase = row0 + w * 16 + (lane >> 4) * 4;
    #pragma unroll
    for (int nt = 0; nt < 8; ++nt){
      int col = nt * 16 + lr;
      float bb = b2[col];
      #pragma unroll
      for (int j = 0; j < 4; ++j){
        int row = rbase + j;
        if (row < M){
          float v = acc[nt][j] + bb;
          if (!LAST) v = fmaxf(v, 0.f);
          out[(size_t)row * D + col] = f2bf(v);
        }
      }
    }
  }
}

// ---------------- Global add pool (batch sorted), h is bf16 ----------------

__global__ __launch_bounds__(256) void k_pool(const unsigned short* __restrict__ hb, const int* __restrict__ batch,
                                              float* __restrict__ hG, int N){
  int g = blockIdx.x * 256 + threadIdx.x;
  int chunk = g >> 5;        // 16-node run
  int dg = g & 31;           // 4-dim group
  int n0 = chunk * 16;
  if (n0 >= N) return;
  int n1 = n0 + 16; if (n1 > N) n1 = N;
  float ax = 0.f, ay = 0.f, az = 0.f, aw = 0.f;
  int cur = batch[n0];
  for (int n = n0; n < n1; ++n){
    int b = batch[n];
    uint2 v = *(const uint2*)&hb[(size_t)n * D + dg * 4];
    if (b != cur){
      float* p = &hG[(size_t)cur * D + dg * 4];
      atomicAdd(p + 0, ax); atomicAdd(p + 1, ay); atomicAdd(p + 2, az); atomicAdd(p + 3, aw);
      ax = ay = az = aw = 0.f; cur = b;
    }
    ax += bflo(v.x); ay += bfhi(v.x); az += bflo(v.y); aw += bfhi(v.y);
  }
  float* p = &hG[(size_t)cur * D + dg * 4];
  atomicAdd(p + 0, ax); atomicAdd(p + 1, ay); atomicAdd(p + 2, az); atomicAdd(p + 3, aw);
}

// ---------------- Head ----------------

__global__ __launch_bounds__(64) void k_head(const float* __restrict__ hG, const float* __restrict__ lw,
                                             const float* __restrict__ lb, float* __restrict__ out){
  int gph = blockIdx.x;
  int lane = threadIdx.x;
  float logit = -INFINITY;
  if (lane < 10){
    float s = lb[lane];
    const float* hg = &hG[(size_t)gph * D];
    #pragma unroll 8
    for (int k = 0; k < D; ++k) s += hg[k] * lw[k * 10 + lane];
    logit = s;
  }
  float m = logit;
  for (int off = 32; off; off >>= 1) m = fmaxf(m, __shfl_down(m, off));
  m = __shfl(m, 0);
  float e = (lane < 10) ? expf(logit - m) : 0.f;
  float ssum = e;
  for (int off = 32; off; off >>= 1) ssum += __shfl_down(ssum, off);
  ssum = __shfl(ssum, 0);
  if (lane < 10) out[(size_t)gph * 10 + lane] = logit - m - logf(ssum);
}

// ---------------- launch ----------------

extern "C" void kernel_launch(void* const* d_in, const int* in_sizes, int n_in,
                              void* d_out, int out_size, void* d_ws, size_t ws_size,
                              hipStream_t stream){
  const float* x  = (const float*)d_in[0];
  const int*   ei = (const int*)d_in[1];
  const int*   batch = (const int*)d_in[2];
  const float* W1 = (const float*)d_in[3];
  const float* b1 = (const float*)d_in[4];
  const float* W2 = (const float*)d_in[5];
  const float* b2 = (const float*)d_in[6];
  const float* lw = (const float*)d_in[7];
  const float* lb = (const float*)d_in[8];
  float* out = (float*)d_out;

  int N = in_sizes[0] / D;       // 50000
  int E = in_sizes[1] / 2;       // 600000
  int G = out_size / (D + 10);   // 500
  const int* src = ei;
  const int* dst = ei + E;

  char* w = (char*)d_ws;
  size_t off = 0;
  auto alloc = [&](size_t bytes) -> char* {
    char* p = w + off;
    off = (off + bytes + 255) & ~(size_t)255;
    return p;
  };
  unsigned short* h_bf  = (unsigned short*)alloc((size_t)N * D * 2);
  unsigned short* z_bf  = (unsigned short*)alloc((size_t)N * D * 2);
  unsigned short* WT    = (unsigned short*)alloc((size_t)8 * D * D * 2);
  int nb = (N + 255) / 256;
  int* row_start = (int*)alloc((size_t)(N + 1) * 4);
  int* counts    = (int*)alloc((size_t)N * 4);
  int* partial   = (int*)alloc((size_t)nb * 4);
  int* poff      = (int*)alloc((size_t)nb * 4);
  int* srcs      = (int*)alloc((size_t)E * 4);

  hipMemsetAsync(counts, 0, (size_t)N * 4, stream);
  hipMemsetAsync(d_out,  0, (size_t)out_size * 4, stream);

  int n8 = N * D / 8;
  k_cast<<<(n8 + 255) / 256, 256, 0, stream>>>(x, h_bf, n8);
  k_packWT<<<512, 256, 0, stream>>>(W1, W2, WT);

  int ge = (E + 255) / 256;
  k_count<<<ge, 256, 0, stream>>>(dst, counts, E);
  k_blocksum<<<nb, 256, 0, stream>>>(counts, partial, N);
  k_scanpartial<<<1, 256, 0, stream>>>(partial, poff, nb, row_start, N);
  k_blockscan<<<nb, 256, 0, stream>>>(counts, poff, row_start, N);
  k_fill<<<ge, 256, 0, stream>>>(src, dst, row_start, counts, srcs, E);

  int nwave = (N + 3) / 4;                 // 4 nodes per wave
  int gagg = (nwave * 64 + 255) / 256;
  int gm = (N + 63) / 64;
  for (int i = 0; i < 4; ++i){
    k_agg<<<gagg, 256, 0, stream>>>(h_bf, row_start, srcs, z_bf, N);
    if (i < 3)
      k_mlp<0><<<gm, 256, 0, stream>>>(z_bf, WT + (size_t)i * D * D, b1 + (size_t)i * D,
                                       WT + (size_t)(4 + i) * D * D, b2 + (size_t)i * D, h_bf, N);
    else
      k_mlp<1><<<gm, 256, 0, stream>>>(z_bf, WT + (size_t)i * D * D, b1 + (size_t)i * D,
                                       WT + (size_t)(4 + i) * D * D, b2 + (size_t)i * D, h_bf, N);
  }

  int gp = (((N + 15) / 16) * 32 + 255) / 256;
  k_pool<<<gp, 256, 0, stream>>>(h_bf, batch, out, N);
  k_head<<<G, 64, 0, stream>>>(out, lw, lb, out + (size_t)G * D);
}